// Round 5
// baseline (306.451 us; speedup 1.0000x reference)
//
#include <hip/hip_runtime.h>

// ---------------------------------------------------------------------------
// FlaxAttention: x@Wqkv -> LN(q),LN(k) -> causal flash attn -> ctx@out_W
// B=2 S=2048 D=2048 H=16 Dh=128. All matmuls bf16 MFMA (fp32 accum).
// ---------------------------------------------------------------------------

typedef float f32x4 __attribute__((ext_vector_type(4)));
typedef short s16x8 __attribute__((ext_vector_type(8)));
typedef short s16x4 __attribute__((ext_vector_type(4)));

static __device__ __forceinline__ unsigned short f2bf(float f) {
  unsigned u = __builtin_bit_cast(unsigned, f);
  unsigned r = u + 0x7fffu + ((u >> 16) & 1u);   // RNE
  return (unsigned short)(r >> 16);
}
static __device__ __forceinline__ float bf2f(unsigned short s) {
  unsigned u = ((unsigned)s) << 16;
  return __builtin_bit_cast(float, u);
}

static __device__ __forceinline__ void gload_lds16(const unsigned short* g, unsigned short* l) {
  __builtin_amdgcn_global_load_lds((const __attribute__((address_space(1))) void*)g,
                                   (__attribute__((address_space(3))) void*)l, 16, 0, 0);
}

// --------------------------- fp32 -> bf16 convert ---------------------------
__global__ __launch_bounds__(256) void k_cvt4(const float4* __restrict__ in,
                                              s16x4* __restrict__ out, int n) {
  int i = blockIdx.x * 256 + threadIdx.x;
  if (i >= n) return;
  float4 v = in[i];
  s16x4 o = { (short)f2bf(v.x), (short)f2bf(v.y), (short)f2bf(v.z), (short)f2bf(v.w) };
  out[i] = o;
}

// ------------------- W [K][N] f32 -> W^T [N][K] bf16 ------------------------
__global__ __launch_bounds__(256) void k_twT(const float* __restrict__ in,
                                             unsigned short* __restrict__ out,
                                             int K, int N) {
  __shared__ float tile[32][33];
  const int n0 = blockIdx.x * 32, k0 = blockIdx.y * 32;
  const int tx = threadIdx.x & 31, ty = threadIdx.x >> 5;
#pragma unroll
  for (int rr = 0; rr < 4; ++rr) {
    int kr = ty + rr * 8;
    tile[kr][tx] = in[(size_t)(k0 + kr) * N + n0 + tx];
  }
  __syncthreads();
#pragma unroll
  for (int rr = 0; rr < 4; ++rr) {
    int nr = ty + rr * 8;
    out[(size_t)(n0 + nr) * K + k0 + tx] = f2bf(tile[tx][nr]);
  }
}

// --------- 128x256 GEMM, BK=64, 3-deep LDS pipeline (bf16 MFMA) -------------
// C[M][N] = A[M][K] * Bt[N][K]^T. 8 waves (2Mx4N), per-wave C = 64x128.
// LDS 144KB = 3 buffers x (A 16KB + B 32KB). During tile s we issue tile
// s+2's 6 global_load_lds (2 A + 4 B), so every tile's loads have ~2 K-tiles
// of MFMA (~2000cy) to land -- HBM latency fully hidden.
// Per K-tile: [stage(s+2)] -> vmcnt(12) gate -> barrier -> 16 ds_read_b128 +
// 32 MFMA -> barrier. vmcnt(12) = the 12 newer loads of tiles s+1,s+2; the
// gate therefore means tile s's 6 loads landed. Overwrite safety: the buffer
// staged at iter s (buf (s+2)%3 == (s-1)%3) was last read at iter s-1; those
// reads were consumed by MFMA (lgkm-forced) before the end-of-(s-1) barrier,
// which every wave passed before any stage issue at iter s.
// LDS swizzle: 16B-slot ^= (row&7), source pre-swizzled (rule #21).
// Block mapping: XCD (bid&7) owns npx contiguous 256-col B panels (L2-
// resident); within an XCD, m-major with n innermost (A-tile reuse).
template <int BF16OUT>
__global__ __launch_bounds__(512, 2) void k_g3b(const unsigned short* __restrict__ A,
                                                const unsigned short* __restrict__ Bt,
                                                void* __restrict__ Cout,
                                                int N, int K, int npx) {
  __shared__ unsigned short sA[3 * 128 * 64];       // 48KB [buf][128][64]
  __shared__ unsigned short sB[3 * 256 * 64];       // 96KB [buf][256][64]
  const int t = threadIdx.x;
  const int wid = t >> 6, lane = t & 63, g = lane >> 4, l15 = lane & 15;
  const int wm2 = wid >> 2, wn2 = wid & 3;
  const int xr = l15 & 7;

  const int xcd = (int)blockIdx.x & 7, idx = (int)blockIdx.x >> 3;
  const int m0 = (idx / npx) * 128;
  const int n0 = (xcd * npx + idx % npx) * 256;

  // staging: thread -> (row = j*64 + (t>>3), 16B slot t&7), source pre-swizzled
  const int srow = t >> 3;
  const int sslot = (t & 7) ^ (srow & 7);
  const unsigned short* pA = A  + (size_t)(m0 + srow) * K + sslot * 8;
  const unsigned short* pB = Bt + (size_t)(n0 + srow) * K + sslot * 8;

  auto stage = [&](int kt, int buf) {
#pragma unroll
    for (int j = 0; j < 2; ++j)
      gload_lds16(pA + (size_t)(j * 64) * K + kt * 64,
                  sA + buf * 8192 + j * 4096 + t * 8);
#pragma unroll
    for (int j = 0; j < 4; ++j)
      gload_lds16(pB + (size_t)(j * 64) * K + kt * 64,
                  sB + buf * 16384 + j * 4096 + t * 8);
  };

  const int sl0 = (g ^ xr) * 8, sl1 = ((4 + g) ^ xr) * 8;   // ks=0,1 slots
  const int arow = wm2 * 64 + l15;                  // + fm*16
  const int brow = wn2 * 32 + l15;                  // + h*128 + fn*16

  f32x4 acc[2][4][2];
#pragma unroll
  for (int h = 0; h < 2; ++h)
#pragma unroll
    for (int fm = 0; fm < 4; ++fm)
#pragma unroll
      for (int fn = 0; fn < 2; ++fn) acc[h][fm][fn] = (f32x4){0.f, 0.f, 0.f, 0.f};

  const int NK = K >> 6;
  stage(0, 0);
  stage(1, 1);
  int b0 = 0, b1 = 1, b2 = 2;

  for (int s = 0; s < NK; ++s) {
    if (s + 2 < NK) stage(s + 2, b2);

    if (s + 2 < NK)      asm volatile("s_waitcnt vmcnt(12)" ::: "memory");
    else if (s + 1 < NK) asm volatile("s_waitcnt vmcnt(6)" ::: "memory");
    else                 asm volatile("s_waitcnt vmcnt(0)" ::: "memory");
    __builtin_amdgcn_sched_barrier(0);
    __builtin_amdgcn_s_barrier();
    __builtin_amdgcn_sched_barrier(0);

    const unsigned short* aT = sA + b0 * 8192;
    const unsigned short* bT = sB + b0 * 16384;
    s16x8 af[4][2], bfr[2][2][2];
#pragma unroll
    for (int fm = 0; fm < 4; ++fm) {
      af[fm][0] = *(const s16x8*)&aT[(arow + fm * 16) * 64 + sl0];
      af[fm][1] = *(const s16x8*)&aT[(arow + fm * 16) * 64 + sl1];
    }
#pragma unroll
    for (int h = 0; h < 2; ++h)
#pragma unroll
      for (int fn = 0; fn < 2; ++fn) {
        bfr[h][fn][0] = *(const s16x8*)&bT[(h * 128 + brow + fn * 16) * 64 + sl0];
        bfr[h][fn][1] = *(const s16x8*)&bT[(h * 128 + brow + fn * 16) * 64 + sl1];
      }

    __builtin_amdgcn_s_setprio(1);
#pragma unroll
    for (int fm = 0; fm < 4; ++fm)
#pragma unroll
      for (int h = 0; h < 2; ++h)
#pragma unroll
        for (int fn = 0; fn < 2; ++fn)
#pragma unroll
          for (int ks = 0; ks < 2; ++ks)
            acc[h][fm][fn] = __builtin_amdgcn_mfma_f32_16x16x32_bf16(
                af[fm][ks], bfr[h][fn][ks], acc[h][fm][fn], 0, 0, 0);
    __builtin_amdgcn_s_setprio(0);

    __builtin_amdgcn_sched_barrier(0);
    __builtin_amdgcn_s_barrier();

    int tmp = b0; b0 = b1; b1 = b2; b2 = tmp;
  }

  // epilogue
#pragma unroll
  for (int h = 0; h < 2; ++h)
#pragma unroll
    for (int fm = 0; fm < 4; ++fm)
#pragma unroll
      for (int fn = 0; fn < 2; ++fn)
#pragma unroll
        for (int r = 0; r < 4; ++r) {
          const int row = m0 + wm2 * 64 + fm * 16 + g * 4 + r;
          const int col = n0 + h * 128 + wn2 * 32 + fn * 16 + l15;
          if (BF16OUT)
            ((unsigned short*)Cout)[(size_t)row * N + col] = f2bf(acc[h][fm][fn][r]);
          else
            ((float*)Cout)[(size_t)row * N + col] = acc[h][fm][fn][r];
        }
}

// ----------------- in-place LayerNorm on q,k parts of qkv -------------------
// q gets *= q_scale * (1/sqrt(128))*log2(e) so attn uses exp2 directly.
__global__ __launch_bounds__(256) void k_ln(unsigned short* __restrict__ qkv,
                                            const float* __restrict__ qsc,
                                            const float* __restrict__ ksc) {
  __shared__ float red[8];
  const int t = threadIdx.x;
  const int w = t >> 6;
  unsigned short* base = qkv + (size_t)blockIdx.x * 6144;
#pragma unroll
  for (int part = 0; part < 2; ++part) {
    unsigned short* p = base + part * 2048 + t * 8;
    s16x8 v = *(const s16x8*)p;
    float f[8], s = 0.f, q = 0.f;
#pragma unroll
    for (int j = 0; j < 8; j++) { f[j] = bf2f((unsigned short)v[j]); s += f[j]; q += f[j] * f[j]; }
#pragma unroll
    for (int m = 1; m < 64; m <<= 1) { s += __shfl_xor(s, m); q += __shfl_xor(q, m); }
    __syncthreads();
    if ((t & 63) == 0) { red[w] = s; red[4 + w] = q; }
    __syncthreads();
    s = red[0] + red[1] + red[2] + red[3];
    q = red[4] + red[5] + red[6] + red[7];
    float mean = s * (1.f / 2048.f);
    float var = q * (1.f / 2048.f) - mean * mean;
    float inv = rsqrtf(var + 1e-6f);
    const float* sc = part ? ksc : qsc;
    float extra = part ? 1.0f : 0.12751743f;  // (1/sqrt(128))*log2(e)
    s16x8 o;
#pragma unroll
    for (int j = 0; j < 8; j++) o[j] = (short)f2bf((f[j] - mean) * inv * (sc[t * 8 + j] * extra));
    *(s16x8*)p = o;
  }
}

// ------ v part of qkv (bf16) -> v_t [b][h][d][2048], PV-fragment order ------
__global__ __launch_bounds__(256) void k_vT(const unsigned short* __restrict__ qkv,
                                            unsigned short* __restrict__ vt) {
  __shared__ unsigned short tl[64][136];
  const int bh = blockIdx.y;
  const int b = bh >> 4, h = bh & 15;
  const int s0 = blockIdx.x * 64;
  const int t = threadIdx.x;
#pragma unroll
  for (int it = 0; it < 4; ++it) {
    int flat = it * 256 + t;
    int r = flat >> 4, c = flat & 15;
    s16x8 v = *(const s16x8*)(qkv + (size_t)(b * 2048 + s0 + r) * 6144 + 4096 + h * 128 + c * 8);
    *((s16x8*)&tl[r][c * 8]) = v;
  }
  __syncthreads();
#pragma unroll
  for (int it = 0; it < 4; ++it) {
    int flat = it * 256 + t;
    int d = flat >> 3, cs = flat & 7;
    s16x8 o;
#pragma unroll
    for (int e = 0; e < 8; e++) {
      int key = (cs >> 2) * 32 + (e >> 2) * 16 + (cs & 3) * 4 + (e & 3);
      o[e] = (short)tl[key][d];
    }
    *(s16x8*)(vt + (size_t)(bh * 128 + d) * 2048 + s0 + cs * 8) = o;
  }
}

// --------------------------- causal flash attention -------------------------
__global__ __launch_bounds__(256) void k_attn(const unsigned short* __restrict__ qkv,
                                              const unsigned short* __restrict__ vt,
                                              unsigned short* __restrict__ ctx) {
  __shared__ unsigned short sK[2][64 * 128];
  __shared__ unsigned short sV[2][128 * 64];
  const int t = threadIdx.x;
  const int w = t >> 6, lane = t & 63, g = lane >> 4, l15 = lane & 15;
  const int pair = blockIdx.x, h = blockIdx.y, b = blockIdx.z;
  const int qt0 = 31 - pair, qt1 = pair;
  const int n0 = qt0 + 1;
  const int NT = 33;
  const unsigned short* kbase = qkv + (size_t)(b * 2048) * 6144 + 2048 + h * 128;
  const unsigned short* vbase = vt + (size_t)((b * 16 + h) * 128) * 2048;

  auto issue_kv = [&](int k0, int bufi) {
#pragma unroll
    for (int it2 = 0; it2 < 4; ++it2) {
      int flat = it2 * 256 + t;
      int r = flat >> 4, c = flat & 15;
      gload_lds16(kbase + (size_t)(k0 + r) * 6144 + ((c ^ (r & 15)) * 8),
                  (unsigned short*)&sK[bufi][(it2 * 256 + w * 64) * 8]);
    }
#pragma unroll
    for (int it2 = 0; it2 < 4; ++it2) {
      int flat = it2 * 256 + t;
      int d = flat >> 3, z = flat & 7;
      gload_lds16(vbase + (size_t)d * 2048 + k0 + ((z ^ (d & 7)) * 8),
                  (unsigned short*)&sV[bufi][(it2 * 256 + w * 64) * 8]);
    }
  };

  s16x8 bq[4];
  auto load_q = [&](int q0) {
#pragma unroll
    for (int ks = 0; ks < 4; ++ks)
      bq[ks] = *(const s16x8*)(qkv + (size_t)(b * 2048 + q0 + w * 16 + l15) * 6144 +
                               h * 128 + (ks * 4 + g) * 8);
  };

  f32x4 o[8];
  float mrun, lrun;
  auto reset_state = [&]() {
#pragma unroll
    for (int nd = 0; nd < 8; ++nd) o[nd] = (f32x4){0.f, 0.f, 0.f, 0.f};
    mrun = -INFINITY; lrun = 0.f;
  };
  auto write_o = [&](int q0) {
    float ivr[4];
#pragma unroll
    for (int r = 0; r < 4; ++r) ivr[r] = 1.0f / __shfl(lrun, 4 * g + r);
#pragma unroll
    for (int nd = 0; nd < 8; ++nd) {
      const int col = h * 128 + nd * 16 + l15;
#pragma unroll
      for (int r = 0; r < 4; ++r) {
        const int row = b * 2048 + q0 + w * 16 + 4 * g + r;
        ctx[(size_t)row * 2048 + col] = f2bf(o[nd][r] * ivr[r]);
      }
    }
  };

  reset_state();
  load_q(qt0 * 64);
  issue_kv(0, 0);
  int cur = 0;

  for (int it = 0; it < NT; ++it) {
    const int seg = (it < n0) ? 0 : 1;
    const int qt = seg ? qt1 : qt0;
    const int kt = seg ? it - n0 : it;

    if (it + 1 < NT) {
      const int kn = (it + 1 < n0) ? it + 1 : it + 1 - n0;
      issue_kv(kn * 64, cur ^ 1);
      asm volatile("s_waitcnt vmcnt(8)" ::: "memory");
    } else {
      asm volatile("s_waitcnt vmcnt(0)" ::: "memory");
    }
    __builtin_amdgcn_sched_barrier(0);
    __builtin_amdgcn_s_barrier();

    if (seg == 1 && kt == 0) {
      write_o(qt0 * 64);
      reset_state();
      load_q(qt1 * 64);
    }

    const unsigned short* sKc = &sK[cur][0];
    const unsigned short* sVc = &sV[cur][0];

    f32x4 st[4];
#pragma unroll
    for (int mi = 0; mi < 4; ++mi) st[mi] = (f32x4){0.f, 0.f, 0.f, 0.f};
#pragma unroll
    for (int mi = 0; mi < 4; ++mi) {
#pragma unroll
      for (int ks = 0; ks < 4; ++ks) {
        s16x8 ak = *(const s16x8*)&sKc[(mi * 16 + l15) * 128 + (((ks * 4 + g) ^ l15) * 8)];
        st[mi] = __builtin_amdgcn_mfma_f32_16x16x32_bf16(ak, bq[ks], st[mi], 0, 0, 0);
      }
    }

    if (kt == qt) {
      const int qloc = w * 16 + l15;
#pragma unroll
      for (int mi = 0; mi < 4; ++mi)
#pragma unroll
        for (int r = 0; r < 4; ++r)
          if (mi * 16 + 4 * g + r > qloc) st[mi][r] = -INFINITY;
    }

    float mt = -INFINITY;
#pragma unroll
    for (int mi = 0; mi < 4; ++mi)
#pragma unroll
      for (int r = 0; r < 4; ++r) mt = fmaxf(mt, st[mi][r]);
    mt = fmaxf(mt, __shfl_xor(mt, 16));
    mt = fmaxf(mt, __shfl_xor(mt, 32));

    if (!__all(mt <= mrun + 8.f)) {
      const float mnew = fmaxf(mrun, mt);
      const float alpha = exp2f(mrun - mnew);
      lrun *= alpha;
      float ar[4];
#pragma unroll
      for (int r = 0; r < 4; ++r) ar[r] = __shfl(alpha, 4 * g + r);
#pragma unroll
      for (int nd = 0; nd < 8; ++nd)
#pragma unroll
        for (int r = 0; r < 4; ++r) o[nd][r] *= ar[r];
      mrun = mnew;
    }

    float ls = 0.f;
#pragma unroll
    for (int mi = 0; mi < 4; ++mi)
#pragma unroll
      for (int r = 0; r < 4; ++r) {
        float pp = exp2f(st[mi][r] - mrun);
        st[mi][r] = pp;
        ls += pp;
      }
    ls += __shfl_xor(ls, 16);
    ls += __shfl_xor(ls, 32);
    lrun += ls;

    s16x8 pa01, pa23;
#pragma unroll
    for (int j = 0; j < 8; ++j) {
      pa01[j] = (short)f2bf(st[j >> 2][j & 3]);
      pa23[j] = (short)f2bf(st[2 + (j >> 2)][j & 3]);
    }

#pragma unroll
    for (int nd = 0; nd < 8; ++nd) {
      const int d = nd * 16 + l15;
      const int zs = d & 7;
      s16x8 bv0 = *(const s16x8*)&sVc[d * 64 + ((g ^ zs) * 8)];
      s16x8 bv1 = *(const s16x8*)&sVc[d * 64 + (((4 + g) ^ zs) * 8)];
      o[nd] = __builtin_amdgcn_mfma_f32_16x16x32_bf16(pa01, bv0, o[nd], 0, 0, 0);
      o[nd] = __builtin_amdgcn_mfma_f32_16x16x32_bf16(pa23, bv1, o[nd], 0, 0, 0);
    }

    __builtin_amdgcn_sched_barrier(0);
    __builtin_amdgcn_s_barrier();
    cur ^= 1;
  }
  write_o(qt1 * 64);
}

// ---------------------------------------------------------------------------
extern "C" void kernel_launch(void* const* d_in, const int* in_sizes, int n_in,
                              void* d_out, int out_size, void* d_ws, size_t ws_size,
                              hipStream_t stream) {
  (void)in_sizes; (void)n_in; (void)out_size; (void)ws_size;
  const float* x    = (const float*)d_in[0];
  const float* Wqkv = (const float*)d_in[1];
  const float* qsc  = (const float*)d_in[2];
  const float* ksc  = (const float*)d_in[3];
  const float* outW = (const float*)d_in[4];

  char* ws = (char*)d_ws;
  unsigned short* xb  = (unsigned short*)(ws);              // 16.8MB (reused as ctx)
  unsigned short* wT  = (unsigned short*)(ws + 16777216);   // 25.2MB  Wqkv^T bf16
  unsigned short* owT = (unsigned short*)(ws + 41943040);   // 8.4MB   out_W^T bf16
  unsigned short* qkv = (unsigned short*)(ws + 50331648);   // 50.3MB  qkv bf16 (LN in place)
  unsigned short* vt  = (unsigned short*)(ws + 100663296);  // 16.8MB  v^T per head
  unsigned short* ctx = xb;                                 // x dead after QKV GEMM

  k_cvt4<<<8192, 256, 0, stream>>>((const float4*)x, (s16x4*)xb, 2097152);
  k_twT<<<dim3(192, 64), 256, 0, stream>>>(Wqkv, wT, 2048, 6144);
  k_twT<<<dim3(64, 64), 256, 0, stream>>>(outW, owT, 2048, 2048);
  k_g3b<1><<<768, 512, 0, stream>>>(xb, wT, qkv, 6144, 2048, 3);
  k_ln<<<4096, 256, 0, stream>>>(qkv, qsc, ksc);
  k_vT<<<dim3(32, 32), 256, 0, stream>>>(qkv, vt);
  k_attn<<<dim3(16, 16, 2), 256, 0, stream>>>(qkv, vt, ctx);
  k_g3b<0><<<256, 512, 0, stream>>>(ctx, owT, d_out, 2048, 2048, 1);
}

// Round 6
// 288.272 us; speedup vs baseline: 1.0631x; 1.0631x over previous
//
#include <hip/hip_runtime.h>

// ---------------------------------------------------------------------------
// FlaxAttention: x@Wqkv -> LN(q),LN(k) -> causal flash attn -> ctx@out_W
// B=2 S=2048 D=2048 H=16 Dh=128. All matmuls bf16 MFMA (fp32 accum).
// ---------------------------------------------------------------------------

typedef float f32x4 __attribute__((ext_vector_type(4)));
typedef short s16x8 __attribute__((ext_vector_type(8)));
typedef short s16x4 __attribute__((ext_vector_type(4)));

static __device__ __forceinline__ unsigned short f2bf(float f) {
  unsigned u = __builtin_bit_cast(unsigned, f);
  unsigned r = u + 0x7fffu + ((u >> 16) & 1u);   // RNE
  return (unsigned short)(r >> 16);
}
static __device__ __forceinline__ float bf2f(unsigned short s) {
  unsigned u = ((unsigned)s) << 16;
  return __builtin_bit_cast(float, u);
}

static __device__ __forceinline__ void gload_lds16(const unsigned short* g, unsigned short* l) {
  __builtin_amdgcn_global_load_lds((const __attribute__((address_space(1))) void*)g,
                                   (__attribute__((address_space(3))) void*)l, 16, 0, 0);
}

// --------------------------- fp32 -> bf16 convert ---------------------------
__global__ __launch_bounds__(256) void k_cvt4(const float4* __restrict__ in,
                                              s16x4* __restrict__ out, int n) {
  int i = blockIdx.x * 256 + threadIdx.x;
  if (i >= n) return;
  float4 v = in[i];
  s16x4 o = { (short)f2bf(v.x), (short)f2bf(v.y), (short)f2bf(v.z), (short)f2bf(v.w) };
  out[i] = o;
}

// ------------------- W [K][N] f32 -> W^T [N][K] bf16 ------------------------
__global__ __launch_bounds__(256) void k_twT(const float* __restrict__ in,
                                             unsigned short* __restrict__ out,
                                             int K, int N) {
  __shared__ float tile[32][33];
  const int n0 = blockIdx.x * 32, k0 = blockIdx.y * 32;
  const int tx = threadIdx.x & 31, ty = threadIdx.x >> 5;
#pragma unroll
  for (int rr = 0; rr < 4; ++rr) {
    int kr = ty + rr * 8;
    tile[kr][tx] = in[(size_t)(k0 + kr) * N + n0 + tx];
  }
  __syncthreads();
#pragma unroll
  for (int rr = 0; rr < 4; ++rr) {
    int nr = ty + rr * 8;
    out[(size_t)(n0 + nr) * K + k0 + tx] = f2bf(tile[tx][nr]);
  }
}

// ------ 128x256 GEMM, BK=64, 2-phase compute + 3-deep ring (bf16 MFMA) ------
// C[M][N] = A[M][K] * Bt[N][K]^T. 8 waves (2Mx4N), per-wave C = 64x64
// (cols split h*128 + wn2*32). LDS 144KB = 3 ring slots x (A 16KB + B 32KB).
// During iter s we stage tile s+2 -> tile s's loads issued ~2 K-tiles early.
// Per K-tile: 2 phases (R3's empirically-best granularity):
//   p0: reads A(8)+B-half0(4) [tile s, gated at p1(s-1)]; stage A,B0(s+2);
//       vmcnt(10) [=> B1(s) landed]; barrier; 16 MFMA h0; barrier.
//   p1: reads B-half1(4); stage B1(s+2); vmcnt(8) [=> A,B0(s+1) landed];
//       barrier; 16 MFMA h1 (af reused); barrier.
// Gate proof (issue stream ...A,B0(s+1)|B1(s+1)|A,B0(s+2)|B1(s+2)...):
//   G0(s) needs B1(s): newer = 4+2+4 = 10 -> vmcnt(10).
//   G1(s) needs A,B0(s+1): newer = 2+4+2 = 8 -> vmcnt(8).
//   Tails: s==NK-2 -> 6/2; s==NK-1 -> 0/none. Never a mid-loop drain.
// Overwrite safety: stage at iter s targets slot of tile s-1, whose last
// reads completed >= 2 barriers earlier.
// LDS swizzle: 16B-slot ^= (row&7), source pre-swizzled (rule #21).
// Block mapping: XCD (bid&7) owns npx contiguous 256-col B panels (L2-
// resident); within an XCD, m-major with n innermost (A-tile reuse).
template <int BF16OUT>
__global__ __launch_bounds__(512, 2) void k_gp3(const unsigned short* __restrict__ A,
                                                const unsigned short* __restrict__ Bt,
                                                void* __restrict__ Cout,
                                                int N, int K, int npx) {
  __shared__ unsigned short sA[3 * 128 * 64];       // 48KB [slot][128][64]
  __shared__ unsigned short sB[3 * 256 * 64];       // 96KB [slot][256][64]
  const int t = threadIdx.x;
  const int wid = t >> 6, lane = t & 63, g = lane >> 4, l15 = lane & 15;
  const int wm2 = wid >> 2, wn2 = wid & 3;
  const int xr = l15 & 7;

  const int xcd = (int)blockIdx.x & 7, idx = (int)blockIdx.x >> 3;
  const int m0 = (idx / npx) * 128;
  const int n0 = (xcd * npx + idx % npx) * 256;

  // staging: thread -> (row = j*64 + (t>>3), 16B slot t&7), source pre-swizzled
  const int srow = t >> 3;
  const int sslot = (t & 7) ^ (srow & 7);
  const unsigned short* pA = A  + (size_t)(m0 + srow) * K + sslot * 8;
  const unsigned short* pB = Bt + (size_t)(n0 + srow) * K + sslot * 8;

  auto stageA = [&](int kt, int buf) {
#pragma unroll
    for (int j = 0; j < 2; ++j)
      gload_lds16(pA + (size_t)(j * 64) * K + kt * 64,
                  sA + buf * 8192 + j * 4096 + t * 8);
  };
  auto stageB0 = [&](int kt, int buf) {
#pragma unroll
    for (int j = 0; j < 2; ++j)
      gload_lds16(pB + (size_t)(j * 64) * K + kt * 64,
                  sB + buf * 16384 + j * 4096 + t * 8);
  };
  auto stageB1 = [&](int kt, int buf) {
#pragma unroll
    for (int j = 0; j < 2; ++j)
      gload_lds16(pB + (size_t)(128 + j * 64) * K + kt * 64,
                  sB + buf * 16384 + 8192 + j * 4096 + t * 8);
  };

  const int sl0 = (g ^ xr) * 8, sl1 = ((4 + g) ^ xr) * 8;   // ks=0,1 slots
  const int arow = wm2 * 64 + l15;                  // + fm*16
  const int brow = wn2 * 32 + l15;                  // + h*128 + fn*16

  f32x4 acc[2][4][2];
#pragma unroll
  for (int h = 0; h < 2; ++h)
#pragma unroll
    for (int fm = 0; fm < 4; ++fm)
#pragma unroll
      for (int fn = 0; fn < 2; ++fn) acc[h][fm][fn] = (f32x4){0.f, 0.f, 0.f, 0.f};

  const int NK = K >> 6;
  // prologue (order matters for gate counts): A,B0,B1(0); A,B0,B1(1)
  stageA(0, 0); stageB0(0, 0); stageB1(0, 0);
  stageA(1, 1); stageB0(1, 1); stageB1(1, 1);
  asm volatile("s_waitcnt vmcnt(8)" ::: "memory");  // A(0),B0(0) landed
  __builtin_amdgcn_sched_barrier(0);
  asm volatile("s_barrier" ::: "memory");
  __builtin_amdgcn_sched_barrier(0);

  int b0 = 0, b2 = 2;                               // read slot, stage slot
  for (int s = 0; s < NK; ++s) {
    const unsigned short* aT = sA + b0 * 8192;
    const unsigned short* bT = sB + b0 * 16384;
    s16x8 af[4][2], bfr[2][2];

    // ---------------- phase 0: C cols [0,128) ----------------
#pragma unroll
    for (int fm = 0; fm < 4; ++fm) {
      af[fm][0] = *(const s16x8*)&aT[(arow + fm * 16) * 64 + sl0];
      af[fm][1] = *(const s16x8*)&aT[(arow + fm * 16) * 64 + sl1];
    }
#pragma unroll
    for (int fn = 0; fn < 2; ++fn) {
      bfr[fn][0] = *(const s16x8*)&bT[(brow + fn * 16) * 64 + sl0];
      bfr[fn][1] = *(const s16x8*)&bT[(brow + fn * 16) * 64 + sl1];
    }
    if (s + 2 < NK) { stageA(s + 2, b2); stageB0(s + 2, b2); }
    if (s + 2 < NK)       asm volatile("s_waitcnt vmcnt(10)" ::: "memory");
    else if (s == NK - 2) asm volatile("s_waitcnt vmcnt(6)"  ::: "memory");
    else                  asm volatile("s_waitcnt vmcnt(0)"  ::: "memory");
    __builtin_amdgcn_sched_barrier(0);
    asm volatile("s_barrier" ::: "memory");
    __builtin_amdgcn_sched_barrier(0);
    __builtin_amdgcn_s_setprio(1);
#pragma unroll
    for (int fm = 0; fm < 4; ++fm)
#pragma unroll
      for (int fn = 0; fn < 2; ++fn)
#pragma unroll
        for (int ks = 0; ks < 2; ++ks)
          acc[0][fm][fn] = __builtin_amdgcn_mfma_f32_16x16x32_bf16(
              af[fm][ks], bfr[fn][ks], acc[0][fm][fn], 0, 0, 0);
    __builtin_amdgcn_s_setprio(0);
    __builtin_amdgcn_sched_barrier(0);
    asm volatile("s_barrier" ::: "memory");

    // ---------------- phase 1: C cols [128,256) --------------
#pragma unroll
    for (int fn = 0; fn < 2; ++fn) {
      bfr[fn][0] = *(const s16x8*)&bT[8192 + (brow + fn * 16) * 64 + sl0];
      bfr[fn][1] = *(const s16x8*)&bT[8192 + (brow + fn * 16) * 64 + sl1];
    }
    if (s + 2 < NK) stageB1(s + 2, b2);
    if (s + 2 < NK)       asm volatile("s_waitcnt vmcnt(8)" ::: "memory");
    else if (s == NK - 2) asm volatile("s_waitcnt vmcnt(2)" ::: "memory");
    // s == NK-1: nothing left to gate
    __builtin_amdgcn_sched_barrier(0);
    asm volatile("s_barrier" ::: "memory");
    __builtin_amdgcn_sched_barrier(0);
    __builtin_amdgcn_s_setprio(1);
#pragma unroll
    for (int fm = 0; fm < 4; ++fm)
#pragma unroll
      for (int fn = 0; fn < 2; ++fn)
#pragma unroll
        for (int ks = 0; ks < 2; ++ks)
          acc[1][fm][fn] = __builtin_amdgcn_mfma_f32_16x16x32_bf16(
              af[fm][ks], bfr[fn][ks], acc[1][fm][fn], 0, 0, 0);
    __builtin_amdgcn_s_setprio(0);
    __builtin_amdgcn_sched_barrier(0);
    asm volatile("s_barrier" ::: "memory");

    b0 = (b0 == 2) ? 0 : b0 + 1;
    b2 = (b2 == 2) ? 0 : b2 + 1;
  }

  // epilogue
#pragma unroll
  for (int h = 0; h < 2; ++h)
#pragma unroll
    for (int fm = 0; fm < 4; ++fm)
#pragma unroll
      for (int fn = 0; fn < 2; ++fn)
#pragma unroll
        for (int r = 0; r < 4; ++r) {
          const int row = m0 + wm2 * 64 + fm * 16 + g * 4 + r;
          const int col = n0 + h * 128 + wn2 * 32 + fn * 16 + l15;
          if (BF16OUT)
            ((unsigned short*)Cout)[(size_t)row * N + col] = f2bf(acc[h][fm][fn][r]);
          else
            ((float*)Cout)[(size_t)row * N + col] = acc[h][fm][fn][r];
        }
}

// ----------------- in-place LayerNorm on q,k parts of qkv -------------------
// q gets *= q_scale * (1/sqrt(128))*log2(e) so attn uses exp2 directly.
__global__ __launch_bounds__(256) void k_ln(unsigned short* __restrict__ qkv,
                                            const float* __restrict__ qsc,
                                            const float* __restrict__ ksc) {
  __shared__ float red[8];
  const int t = threadIdx.x;
  const int w = t >> 6;
  unsigned short* base = qkv + (size_t)blockIdx.x * 6144;
#pragma unroll
  for (int part = 0; part < 2; ++part) {
    unsigned short* p = base + part * 2048 + t * 8;
    s16x8 v = *(const s16x8*)p;
    float f[8], s = 0.f, q = 0.f;
#pragma unroll
    for (int j = 0; j < 8; j++) { f[j] = bf2f((unsigned short)v[j]); s += f[j]; q += f[j] * f[j]; }
#pragma unroll
    for (int m = 1; m < 64; m <<= 1) { s += __shfl_xor(s, m); q += __shfl_xor(q, m); }
    __syncthreads();
    if ((t & 63) == 0) { red[w] = s; red[4 + w] = q; }
    __syncthreads();
    s = red[0] + red[1] + red[2] + red[3];
    q = red[4] + red[5] + red[6] + red[7];
    float mean = s * (1.f / 2048.f);
    float var = q * (1.f / 2048.f) - mean * mean;
    float inv = rsqrtf(var + 1e-6f);
    const float* sc = part ? ksc : qsc;
    float extra = part ? 1.0f : 0.12751743f;  // (1/sqrt(128))*log2(e)
    s16x8 o;
#pragma unroll
    for (int j = 0; j < 8; j++) o[j] = (short)f2bf((f[j] - mean) * inv * (sc[t * 8 + j] * extra));
    *(s16x8*)p = o;
  }
}

// ------ v part of qkv (bf16) -> v_t [b][h][d][2048], PV-fragment order ------
__global__ __launch_bounds__(256) void k_vT(const unsigned short* __restrict__ qkv,
                                            unsigned short* __restrict__ vt) {
  __shared__ unsigned short tl[64][136];
  const int bh = blockIdx.y;
  const int b = bh >> 4, h = bh & 15;
  const int s0 = blockIdx.x * 64;
  const int t = threadIdx.x;
#pragma unroll
  for (int it = 0; it < 4; ++it) {
    int flat = it * 256 + t;
    int r = flat >> 4, c = flat & 15;
    s16x8 v = *(const s16x8*)(qkv + (size_t)(b * 2048 + s0 + r) * 6144 + 4096 + h * 128 + c * 8);
    *((s16x8*)&tl[r][c * 8]) = v;
  }
  __syncthreads();
#pragma unroll
  for (int it = 0; it < 4; ++it) {
    int flat = it * 256 + t;
    int d = flat >> 3, cs = flat & 7;
    s16x8 o;
#pragma unroll
    for (int e = 0; e < 8; e++) {
      int key = (cs >> 2) * 32 + (e >> 2) * 16 + (cs & 3) * 4 + (e & 3);
      o[e] = (short)tl[key][d];
    }
    *(s16x8*)(vt + (size_t)(bh * 128 + d) * 2048 + s0 + cs * 8) = o;
  }
}

// --------------------------- causal flash attention -------------------------
__global__ __launch_bounds__(256) void k_attn(const unsigned short* __restrict__ qkv,
                                              const unsigned short* __restrict__ vt,
                                              unsigned short* __restrict__ ctx) {
  __shared__ unsigned short sK[2][64 * 128];
  __shared__ unsigned short sV[2][128 * 64];
  const int t = threadIdx.x;
  const int w = t >> 6, lane = t & 63, g = lane >> 4, l15 = lane & 15;
  const int pair = blockIdx.x, h = blockIdx.y, b = blockIdx.z;
  const int qt0 = 31 - pair, qt1 = pair;
  const int n0 = qt0 + 1;
  const int NT = 33;
  const unsigned short* kbase = qkv + (size_t)(b * 2048) * 6144 + 2048 + h * 128;
  const unsigned short* vbase = vt + (size_t)((b * 16 + h) * 128) * 2048;

  auto issue_kv = [&](int k0, int bufi) {
#pragma unroll
    for (int it2 = 0; it2 < 4; ++it2) {
      int flat = it2 * 256 + t;
      int r = flat >> 4, c = flat & 15;
      gload_lds16(kbase + (size_t)(k0 + r) * 6144 + ((c ^ (r & 15)) * 8),
                  (unsigned short*)&sK[bufi][(it2 * 256 + w * 64) * 8]);
    }
#pragma unroll
    for (int it2 = 0; it2 < 4; ++it2) {
      int flat = it2 * 256 + t;
      int d = flat >> 3, z = flat & 7;
      gload_lds16(vbase + (size_t)d * 2048 + k0 + ((z ^ (d & 7)) * 8),
                  (unsigned short*)&sV[bufi][(it2 * 256 + w * 64) * 8]);
    }
  };

  s16x8 bq[4];
  auto load_q = [&](int q0) {
#pragma unroll
    for (int ks = 0; ks < 4; ++ks)
      bq[ks] = *(const s16x8*)(qkv + (size_t)(b * 2048 + q0 + w * 16 + l15) * 6144 +
                               h * 128 + (ks * 4 + g) * 8);
  };

  f32x4 o[8];
  float mrun, lrun;
  auto reset_state = [&]() {
#pragma unroll
    for (int nd = 0; nd < 8; ++nd) o[nd] = (f32x4){0.f, 0.f, 0.f, 0.f};
    mrun = -INFINITY; lrun = 0.f;
  };
  auto write_o = [&](int q0) {
    float ivr[4];
#pragma unroll
    for (int r = 0; r < 4; ++r) ivr[r] = 1.0f / __shfl(lrun, 4 * g + r);
#pragma unroll
    for (int nd = 0; nd < 8; ++nd) {
      const int col = h * 128 + nd * 16 + l15;
#pragma unroll
      for (int r = 0; r < 4; ++r) {
        const int row = b * 2048 + q0 + w * 16 + 4 * g + r;
        ctx[(size_t)row * 2048 + col] = f2bf(o[nd][r] * ivr[r]);
      }
    }
  };

  reset_state();
  load_q(qt0 * 64);
  issue_kv(0, 0);
  int cur = 0;

  for (int it = 0; it < NT; ++it) {
    const int seg = (it < n0) ? 0 : 1;
    const int qt = seg ? qt1 : qt0;
    const int kt = seg ? it - n0 : it;

    if (it + 1 < NT) {
      const int kn = (it + 1 < n0) ? it + 1 : it + 1 - n0;
      issue_kv(kn * 64, cur ^ 1);
      asm volatile("s_waitcnt vmcnt(8)" ::: "memory");
    } else {
      asm volatile("s_waitcnt vmcnt(0)" ::: "memory");
    }
    __builtin_amdgcn_sched_barrier(0);
    __builtin_amdgcn_s_barrier();

    if (seg == 1 && kt == 0) {
      write_o(qt0 * 64);
      reset_state();
      load_q(qt1 * 64);
    }

    const unsigned short* sKc = &sK[cur][0];
    const unsigned short* sVc = &sV[cur][0];

    f32x4 st[4];
#pragma unroll
    for (int mi = 0; mi < 4; ++mi) st[mi] = (f32x4){0.f, 0.f, 0.f, 0.f};
#pragma unroll
    for (int mi = 0; mi < 4; ++mi) {
#pragma unroll
      for (int ks = 0; ks < 4; ++ks) {
        s16x8 ak = *(const s16x8*)&sKc[(mi * 16 + l15) * 128 + (((ks * 4 + g) ^ l15) * 8)];
        st[mi] = __builtin_amdgcn_mfma_f32_16x16x32_bf16(ak, bq[ks], st[mi], 0, 0, 0);
      }
    }

    if (kt == qt) {
      const int qloc = w * 16 + l15;
#pragma unroll
      for (int mi = 0; mi < 4; ++mi)
#pragma unroll
        for (int r = 0; r < 4; ++r)
          if (mi * 16 + 4 * g + r > qloc) st[mi][r] = -INFINITY;
    }

    float mt = -INFINITY;
#pragma unroll
    for (int mi = 0; mi < 4; ++mi)
#pragma unroll
      for (int r = 0; r < 4; ++r) mt = fmaxf(mt, st[mi][r]);
    mt = fmaxf(mt, __shfl_xor(mt, 16));
    mt = fmaxf(mt, __shfl_xor(mt, 32));

    if (!__all(mt <= mrun + 8.f)) {
      const float mnew = fmaxf(mrun, mt);
      const float alpha = exp2f(mrun - mnew);
      lrun *= alpha;
      float ar[4];
#pragma unroll
      for (int r = 0; r < 4; ++r) ar[r] = __shfl(alpha, 4 * g + r);
#pragma unroll
      for (int nd = 0; nd < 8; ++nd)
#pragma unroll
        for (int r = 0; r < 4; ++r) o[nd][r] *= ar[r];
      mrun = mnew;
    }

    float ls = 0.f;
#pragma unroll
    for (int mi = 0; mi < 4; ++mi)
#pragma unroll
      for (int r = 0; r < 4; ++r) {
        float pp = exp2f(st[mi][r] - mrun);
        st[mi][r] = pp;
        ls += pp;
      }
    ls += __shfl_xor(ls, 16);
    ls += __shfl_xor(ls, 32);
    lrun += ls;

    s16x8 pa01, pa23;
#pragma unroll
    for (int j = 0; j < 8; ++j) {
      pa01[j] = (short)f2bf(st[j >> 2][j & 3]);
      pa23[j] = (short)f2bf(st[2 + (j >> 2)][j & 3]);
    }

#pragma unroll
    for (int nd = 0; nd < 8; ++nd) {
      const int d = nd * 16 + l15;
      const int zs = d & 7;
      s16x8 bv0 = *(const s16x8*)&sVc[d * 64 + ((g ^ zs) * 8)];
      s16x8 bv1 = *(const s16x8*)&sVc[d * 64 + (((4 + g) ^ zs) * 8)];
      o[nd] = __builtin_amdgcn_mfma_f32_16x16x32_bf16(pa01, bv0, o[nd], 0, 0, 0);
      o[nd] = __builtin_amdgcn_mfma_f32_16x16x32_bf16(pa23, bv1, o[nd], 0, 0, 0);
    }

    __builtin_amdgcn_sched_barrier(0);
    __builtin_amdgcn_s_barrier();
    cur ^= 1;
  }
  write_o(qt1 * 64);
}

// ---------------------------------------------------------------------------
extern "C" void kernel_launch(void* const* d_in, const int* in_sizes, int n_in,
                              void* d_out, int out_size, void* d_ws, size_t ws_size,
                              hipStream_t stream) {
  (void)in_sizes; (void)n_in; (void)out_size; (void)ws_size;
  const float* x    = (const float*)d_in[0];
  const float* Wqkv = (const float*)d_in[1];
  const float* qsc  = (const float*)d_in[2];
  const float* ksc  = (const float*)d_in[3];
  const float* outW = (const float*)d_in[4];

  char* ws = (char*)d_ws;
  unsigned short* xb  = (unsigned short*)(ws);              // 16.8MB (reused as ctx)
  unsigned short* wT  = (unsigned short*)(ws + 16777216);   // 25.2MB  Wqkv^T bf16
  unsigned short* owT = (unsigned short*)(ws + 41943040);   // 8.4MB   out_W^T bf16
  unsigned short* qkv = (unsigned short*)(ws + 50331648);   // 50.3MB  qkv bf16 (LN in place)
  unsigned short* vt  = (unsigned short*)(ws + 100663296);  // 16.8MB  v^T per head
  unsigned short* ctx = xb;                                 // x dead after QKV GEMM

  k_cvt4<<<8192, 256, 0, stream>>>((const float4*)x, (s16x4*)xb, 2097152);
  k_twT<<<dim3(192, 64), 256, 0, stream>>>(Wqkv, wT, 2048, 6144);
  k_twT<<<dim3(64, 64), 256, 0, stream>>>(outW, owT, 2048, 2048);
  k_gp3<1><<<768, 512, 0, stream>>>(xb, wT, qkv, 6144, 2048, 3);
  k_ln<<<4096, 256, 0, stream>>>(qkv, qsc, ksc);
  k_vT<<<dim3(32, 32), 256, 0, stream>>>(qkv, vt);
  k_attn<<<dim3(16, 16, 2), 256, 0, stream>>>(qkv, vt, ctx);
  k_gp3<0><<<256, 512, 0, stream>>>(ctx, owT, d_out, 2048, 2048, 1);
}

// Round 7
// 281.430 us; speedup vs baseline: 1.0889x; 1.0243x over previous
//
#include <hip/hip_runtime.h>

// ---------------------------------------------------------------------------
// FlaxAttention: x@Wqkv -> LN(q),LN(k) -> causal flash attn -> ctx@out_W
// B=2 S=2048 D=2048 H=16 Dh=128. All matmuls bf16 MFMA (fp32 accum).
// ---------------------------------------------------------------------------

typedef float f32x4 __attribute__((ext_vector_type(4)));
typedef short s16x8 __attribute__((ext_vector_type(8)));
typedef short s16x4 __attribute__((ext_vector_type(4)));

static __device__ __forceinline__ unsigned short f2bf(float f) {
  unsigned u = __builtin_bit_cast(unsigned, f);
  unsigned r = u + 0x7fffu + ((u >> 16) & 1u);   // RNE
  return (unsigned short)(r >> 16);
}
static __device__ __forceinline__ float bf2f(unsigned short s) {
  unsigned u = ((unsigned)s) << 16;
  return __builtin_bit_cast(float, u);
}

static __device__ __forceinline__ void gload_lds16(const unsigned short* g, unsigned short* l) {
  __builtin_amdgcn_global_load_lds((const __attribute__((address_space(1))) void*)g,
                                   (__attribute__((address_space(3))) void*)l, 16, 0, 0);
}

// --------------------------- fp32 -> bf16 convert ---------------------------
__global__ __launch_bounds__(256) void k_cvt4(const float4* __restrict__ in,
                                              s16x4* __restrict__ out, int n) {
  int i = blockIdx.x * 256 + threadIdx.x;
  if (i >= n) return;
  float4 v = in[i];
  s16x4 o = { (short)f2bf(v.x), (short)f2bf(v.y), (short)f2bf(v.z), (short)f2bf(v.w) };
  out[i] = o;
}

// ------------------- W [K][N] f32 -> W^T [N][K] bf16 ------------------------
__global__ __launch_bounds__(256) void k_twT(const float* __restrict__ in,
                                             unsigned short* __restrict__ out,
                                             int K, int N) {
  __shared__ float tile[32][33];
  const int n0 = blockIdx.x * 32, k0 = blockIdx.y * 32;
  const int tx = threadIdx.x & 31, ty = threadIdx.x >> 5;
#pragma unroll
  for (int rr = 0; rr < 4; ++rr) {
    int kr = ty + rr * 8;
    tile[kr][tx] = in[(size_t)(k0 + kr) * N + n0 + tx];
  }
  __syncthreads();
#pragma unroll
  for (int rr = 0; rr < 4; ++rr) {
    int nr = ty + rr * 8;
    out[(size_t)(n0 + nr) * K + k0 + tx] = f2bf(tile[tx][nr]);
  }
}

// ---- 128 x (NFN*32) GEMM, BK=32, dbuf, 4 waves, 3 blocks/CU (bf16 MFMA) ----
// C[M][N] = A[M][K] * Bt[N][K]^T. Wave = 64 x (NFN*16): acc[4][NFN].
// Small block (48KB LDS @ NFN=8, 256 thr) -> 3 co-resident blocks/CU: barrier
// skew in one block is absorbed by the others (m114 overlap) -- attacks the
// ~2000cy/K-tile lockstep stall R2-R5 all showed (MfmaUtil pinned ~30%).
// Per K-tile: [12 ds_read + 32 MFMA] -> barrier -> stage(t+2 -> freed buf) ->
// vmcnt(S) [retires tile t+1, staged one full iter earlier] -> barrier.
// LDS layout (BK=32: 64B rows, 2 rows per 128B line), conflict-free:
//   elem(r,k) at line (r>>1), 16B-slot ((r&1)*4 + k/8) ^ ((r>>1)&7).
//   Frag reads: 2 lanes/slot-value = 2-way = free. Stage source inverted
//   per-thread: u=(t&7)^((t>>3)&7); srow=2*(t>>3)+(u>>2); sk=(u&3)*8; then
//   write slot == read slot identically (u ^ Lb&7 ^ Lb&7 = t&7). ds_read
//   addresses collapse to base + imm (fm*512 / fn*512 shorts).
template <int BF16OUT, int NFN, int MINW>
__global__ __launch_bounds__(256, MINW) void k_gw(const unsigned short* __restrict__ A,
                                                  const unsigned short* __restrict__ Bt,
                                                  void* __restrict__ Cout,
                                                  int N, int K, int npx) {
  __shared__ unsigned short sA[2 * 128 * 32];            // 16KB
  __shared__ unsigned short sB[2 * NFN * 32 * 32];       // 32KB @NFN=8
  const int t = threadIdx.x;
  const int wid = t >> 6, lane = t & 63, g = lane >> 4, l15 = lane & 15;
  const int wm = wid >> 1, wn = wid & 1;

  // XCD-owned contiguous B panels; m-major, n innermost within XCD.
  const int xcd = (int)blockIdx.x & 7, idx = (int)blockIdx.x >> 3;
  const int m0 = (idx / npx) * 128;
  const int n0 = (xcd * npx + idx % npx) * (NFN * 32);

  // staging source (pre-inverse-swizzled)
  const int u = (t & 7) ^ ((t >> 3) & 7);
  const int srow = 2 * (t >> 3) + (u >> 2);
  const int sk = (u & 3) * 8;
  const unsigned short* pA = A  + (size_t)(m0 + srow) * K + sk;
  const unsigned short* pB = Bt + (size_t)(n0 + srow) * K + sk;

  auto stage = [&](int kt, int buf) {
#pragma unroll
    for (int j = 0; j < 2; ++j)
      gload_lds16(pA + (size_t)(j * 64) * K + kt * 32,
                  sA + buf * 4096 + j * 2048 + t * 8);
#pragma unroll
    for (int j = 0; j < NFN / 2; ++j)
      gload_lds16(pB + (size_t)(j * 64) * K + kt * 32,
                  sB + buf * (NFN * 1024) + j * 2048 + t * 8);
  };

  // frag read bases (shorts); per-read offset = fm*512 / fn*512 (immediates)
  const int si = (((l15 & 1) * 4 + g) ^ ((l15 >> 1) & 7));
  const int baseA = (wm * 32 + (l15 >> 1)) * 64 + si * 8;
  const int baseB = (wn * NFN * 8 + (l15 >> 1)) * 64 + si * 8;

  f32x4 acc[4][NFN];
#pragma unroll
  for (int fm = 0; fm < 4; ++fm)
#pragma unroll
    for (int fn = 0; fn < NFN; ++fn) acc[fm][fn] = (f32x4){0.f, 0.f, 0.f, 0.f};

  const int NK = K >> 5;
  stage(0, 0); stage(1, 1);
  if constexpr (NFN == 8) asm volatile("s_waitcnt vmcnt(6)" ::: "memory");
  else                    asm volatile("s_waitcnt vmcnt(4)" ::: "memory");
  __builtin_amdgcn_sched_barrier(0);
  __builtin_amdgcn_s_barrier();

  for (int s = 0; s < NK; ++s) {
    const unsigned short* aT = sA + (s & 1) * 4096;
    const unsigned short* bT = sB + (s & 1) * (NFN * 1024);

    s16x8 af[4];
#pragma unroll
    for (int fm = 0; fm < 4; ++fm) af[fm] = *(const s16x8*)&aT[baseA + fm * 512];
    __builtin_amdgcn_s_setprio(1);
#pragma unroll
    for (int fn = 0; fn < NFN; ++fn) {
      s16x8 bf = *(const s16x8*)&bT[baseB + fn * 512];
#pragma unroll
      for (int fm = 0; fm < 4; ++fm)
        acc[fm][fn] = __builtin_amdgcn_mfma_f32_16x16x32_bf16(af[fm], bf, acc[fm][fn], 0, 0, 0);
    }
    __builtin_amdgcn_s_setprio(0);

    __builtin_amdgcn_sched_barrier(0);
    __builtin_amdgcn_s_barrier();            // all reads of buf[s&1] complete
    if (s + 2 < NK) {
      stage(s + 2, s & 1);                   // refill the buffer just freed
      if constexpr (NFN == 8) asm volatile("s_waitcnt vmcnt(6)" ::: "memory");
      else                    asm volatile("s_waitcnt vmcnt(4)" ::: "memory");
    } else if (s + 1 < NK) {
      asm volatile("s_waitcnt vmcnt(0)" ::: "memory");
    }
    __builtin_amdgcn_sched_barrier(0);
    __builtin_amdgcn_s_barrier();            // tile s+1 visible to all
  }

  // epilogue
#pragma unroll
  for (int fm = 0; fm < 4; ++fm)
#pragma unroll
    for (int fn = 0; fn < NFN; ++fn)
#pragma unroll
      for (int r = 0; r < 4; ++r) {
        const int row = m0 + wm * 64 + fm * 16 + g * 4 + r;
        const int col = n0 + wn * (NFN * 16) + fn * 16 + l15;
        if (BF16OUT)
          ((unsigned short*)Cout)[(size_t)row * N + col] = f2bf(acc[fm][fn][r]);
        else
          ((float*)Cout)[(size_t)row * N + col] = acc[fm][fn][r];
      }
}

// ----------------- in-place LayerNorm on q,k parts of qkv -------------------
// q gets *= q_scale * (1/sqrt(128))*log2(e) so attn uses exp2 directly.
__global__ __launch_bounds__(256) void k_ln(unsigned short* __restrict__ qkv,
                                            const float* __restrict__ qsc,
                                            const float* __restrict__ ksc) {
  __shared__ float red[8];
  const int t = threadIdx.x;
  const int w = t >> 6;
  unsigned short* base = qkv + (size_t)blockIdx.x * 6144;
#pragma unroll
  for (int part = 0; part < 2; ++part) {
    unsigned short* p = base + part * 2048 + t * 8;
    s16x8 v = *(const s16x8*)p;
    float f[8], s = 0.f, q = 0.f;
#pragma unroll
    for (int j = 0; j < 8; j++) { f[j] = bf2f((unsigned short)v[j]); s += f[j]; q += f[j] * f[j]; }
#pragma unroll
    for (int m = 1; m < 64; m <<= 1) { s += __shfl_xor(s, m); q += __shfl_xor(q, m); }
    __syncthreads();
    if ((t & 63) == 0) { red[w] = s; red[4 + w] = q; }
    __syncthreads();
    s = red[0] + red[1] + red[2] + red[3];
    q = red[4] + red[5] + red[6] + red[7];
    float mean = s * (1.f / 2048.f);
    float var = q * (1.f / 2048.f) - mean * mean;
    float inv = rsqrtf(var + 1e-6f);
    const float* sc = part ? ksc : qsc;
    float extra = part ? 1.0f : 0.12751743f;  // (1/sqrt(128))*log2(e)
    s16x8 o;
#pragma unroll
    for (int j = 0; j < 8; j++) o[j] = (short)f2bf((f[j] - mean) * inv * (sc[t * 8 + j] * extra));
    *(s16x8*)p = o;
  }
}

// ------ v part of qkv (bf16) -> v_t [b][h][d][2048], PV-fragment order ------
__global__ __launch_bounds__(256) void k_vT(const unsigned short* __restrict__ qkv,
                                            unsigned short* __restrict__ vt) {
  __shared__ unsigned short tl[64][136];
  const int bh = blockIdx.y;
  const int b = bh >> 4, h = bh & 15;
  const int s0 = blockIdx.x * 64;
  const int t = threadIdx.x;
#pragma unroll
  for (int it = 0; it < 4; ++it) {
    int flat = it * 256 + t;
    int r = flat >> 4, c = flat & 15;
    s16x8 v = *(const s16x8*)(qkv + (size_t)(b * 2048 + s0 + r) * 6144 + 4096 + h * 128 + c * 8);
    *((s16x8*)&tl[r][c * 8]) = v;
  }
  __syncthreads();
#pragma unroll
  for (int it = 0; it < 4; ++it) {
    int flat = it * 256 + t;
    int d = flat >> 3, cs = flat & 7;
    s16x8 o;
#pragma unroll
    for (int e = 0; e < 8; e++) {
      int key = (cs >> 2) * 32 + (e >> 2) * 16 + (cs & 3) * 4 + (e & 3);
      o[e] = (short)tl[key][d];
    }
    *(s16x8*)(vt + (size_t)(bh * 128 + d) * 2048 + s0 + cs * 8) = o;
  }
}

// --------------------------- causal flash attention -------------------------
__global__ __launch_bounds__(256) void k_attn(const unsigned short* __restrict__ qkv,
                                              const unsigned short* __restrict__ vt,
                                              unsigned short* __restrict__ ctx) {
  __shared__ unsigned short sK[2][64 * 128];
  __shared__ unsigned short sV[2][128 * 64];
  const int t = threadIdx.x;
  const int w = t >> 6, lane = t & 63, g = lane >> 4, l15 = lane & 15;
  const int pair = blockIdx.x, h = blockIdx.y, b = blockIdx.z;
  const int qt0 = 31 - pair, qt1 = pair;
  const int n0 = qt0 + 1;
  const int NT = 33;
  const unsigned short* kbase = qkv + (size_t)(b * 2048) * 6144 + 2048 + h * 128;
  const unsigned short* vbase = vt + (size_t)((b * 16 + h) * 128) * 2048;

  auto issue_kv = [&](int k0, int bufi) {
#pragma unroll
    for (int it2 = 0; it2 < 4; ++it2) {
      int flat = it2 * 256 + t;
      int r = flat >> 4, c = flat & 15;
      gload_lds16(kbase + (size_t)(k0 + r) * 6144 + ((c ^ (r & 15)) * 8),
                  (unsigned short*)&sK[bufi][(it2 * 256 + w * 64) * 8]);
    }
#pragma unroll
    for (int it2 = 0; it2 < 4; ++it2) {
      int flat = it2 * 256 + t;
      int d = flat >> 3, z = flat & 7;
      gload_lds16(vbase + (size_t)d * 2048 + k0 + ((z ^ (d & 7)) * 8),
                  (unsigned short*)&sV[bufi][(it2 * 256 + w * 64) * 8]);
    }
  };

  s16x8 bq[4];
  auto load_q = [&](int q0) {
#pragma unroll
    for (int ks = 0; ks < 4; ++ks)
      bq[ks] = *(const s16x8*)(qkv + (size_t)(b * 2048 + q0 + w * 16 + l15) * 6144 +
                               h * 128 + (ks * 4 + g) * 8);
  };

  f32x4 o[8];
  float mrun, lrun;
  auto reset_state = [&]() {
#pragma unroll
    for (int nd = 0; nd < 8; ++nd) o[nd] = (f32x4){0.f, 0.f, 0.f, 0.f};
    mrun = -INFINITY; lrun = 0.f;
  };
  auto write_o = [&](int q0) {
    float ivr[4];
#pragma unroll
    for (int r = 0; r < 4; ++r) ivr[r] = 1.0f / __shfl(lrun, 4 * g + r);
#pragma unroll
    for (int nd = 0; nd < 8; ++nd) {
      const int col = h * 128 + nd * 16 + l15;
#pragma unroll
      for (int r = 0; r < 4; ++r) {
        const int row = b * 2048 + q0 + w * 16 + 4 * g + r;
        ctx[(size_t)row * 2048 + col] = f2bf(o[nd][r] * ivr[r]);
      }
    }
  };

  reset_state();
  load_q(qt0 * 64);
  issue_kv(0, 0);
  int cur = 0;

  for (int it = 0; it < NT; ++it) {
    const int seg = (it < n0) ? 0 : 1;
    const int qt = seg ? qt1 : qt0;
    const int kt = seg ? it - n0 : it;

    if (it + 1 < NT) {
      const int kn = (it + 1 < n0) ? it + 1 : it + 1 - n0;
      issue_kv(kn * 64, cur ^ 1);
      asm volatile("s_waitcnt vmcnt(8)" ::: "memory");
    } else {
      asm volatile("s_waitcnt vmcnt(0)" ::: "memory");
    }
    __builtin_amdgcn_sched_barrier(0);
    __builtin_amdgcn_s_barrier();

    if (seg == 1 && kt == 0) {
      write_o(qt0 * 64);
      reset_state();
      load_q(qt1 * 64);
    }

    const unsigned short* sKc = &sK[cur][0];
    const unsigned short* sVc = &sV[cur][0];

    f32x4 st[4];
#pragma unroll
    for (int mi = 0; mi < 4; ++mi) st[mi] = (f32x4){0.f, 0.f, 0.f, 0.f};
#pragma unroll
    for (int mi = 0; mi < 4; ++mi) {
#pragma unroll
      for (int ks = 0; ks < 4; ++ks) {
        s16x8 ak = *(const s16x8*)&sKc[(mi * 16 + l15) * 128 + (((ks * 4 + g) ^ l15) * 8)];
        st[mi] = __builtin_amdgcn_mfma_f32_16x16x32_bf16(ak, bq[ks], st[mi], 0, 0, 0);
      }
    }

    if (kt == qt) {
      const int qloc = w * 16 + l15;
#pragma unroll
      for (int mi = 0; mi < 4; ++mi)
#pragma unroll
        for (int r = 0; r < 4; ++r)
          if (mi * 16 + 4 * g + r > qloc) st[mi][r] = -INFINITY;
    }

    float mt = -INFINITY;
#pragma unroll
    for (int mi = 0; mi < 4; ++mi)
#pragma unroll
      for (int r = 0; r < 4; ++r) mt = fmaxf(mt, st[mi][r]);
    mt = fmaxf(mt, __shfl_xor(mt, 16));
    mt = fmaxf(mt, __shfl_xor(mt, 32));

    if (!__all(mt <= mrun + 8.f)) {
      const float mnew = fmaxf(mrun, mt);
      const float alpha = exp2f(mrun - mnew);
      lrun *= alpha;
      float ar[4];
#pragma unroll
      for (int r = 0; r < 4; ++r) ar[r] = __shfl(alpha, 4 * g + r);
#pragma unroll
      for (int nd = 0; nd < 8; ++nd)
#pragma unroll
        for (int r = 0; r < 4; ++r) o[nd][r] *= ar[r];
      mrun = mnew;
    }

    float ls = 0.f;
#pragma unroll
    for (int mi = 0; mi < 4; ++mi)
#pragma unroll
      for (int r = 0; r < 4; ++r) {
        float pp = exp2f(st[mi][r] - mrun);
        st[mi][r] = pp;
        ls += pp;
      }
    ls += __shfl_xor(ls, 16);
    ls += __shfl_xor(ls, 32);
    lrun += ls;

    s16x8 pa01, pa23;
#pragma unroll
    for (int j = 0; j < 8; ++j) {
      pa01[j] = (short)f2bf(st[j >> 2][j & 3]);
      pa23[j] = (short)f2bf(st[2 + (j >> 2)][j & 3]);
    }

#pragma unroll
    for (int nd = 0; nd < 8; ++nd) {
      const int d = nd * 16 + l15;
      const int zs = d & 7;
      s16x8 bv0 = *(const s16x8*)&sVc[d * 64 + ((g ^ zs) * 8)];
      s16x8 bv1 = *(const s16x8*)&sVc[d * 64 + (((4 + g) ^ zs) * 8)];
      o[nd] = __builtin_amdgcn_mfma_f32_16x16x32_bf16(pa01, bv0, o[nd], 0, 0, 0);
      o[nd] = __builtin_amdgcn_mfma_f32_16x16x32_bf16(pa23, bv1, o[nd], 0, 0, 0);
    }

    __builtin_amdgcn_sched_barrier(0);
    __builtin_amdgcn_s_barrier();
    cur ^= 1;
  }
  write_o(qt1 * 64);
}

// ---------------------------------------------------------------------------
extern "C" void kernel_launch(void* const* d_in, const int* in_sizes, int n_in,
                              void* d_out, int out_size, void* d_ws, size_t ws_size,
                              hipStream_t stream) {
  (void)in_sizes; (void)n_in; (void)out_size; (void)ws_size;
  const float* x    = (const float*)d_in[0];
  const float* Wqkv = (const float*)d_in[1];
  const float* qsc  = (const float*)d_in[2];
  const float* ksc  = (const float*)d_in[3];
  const float* outW = (const float*)d_in[4];

  char* ws = (char*)d_ws;
  unsigned short* xb  = (unsigned short*)(ws);              // 16.8MB (reused as ctx)
  unsigned short* wT  = (unsigned short*)(ws + 16777216);   // 25.2MB  Wqkv^T bf16
  unsigned short* owT = (unsigned short*)(ws + 41943040);   // 8.4MB   out_W^T bf16
  unsigned short* qkv = (unsigned short*)(ws + 50331648);   // 50.3MB  qkv bf16 (LN in place)
  unsigned short* vt  = (unsigned short*)(ws + 100663296);  // 16.8MB  v^T per head
  unsigned short* ctx = xb;                                 // x dead after QKV GEMM

  k_cvt4<<<8192, 256, 0, stream>>>((const float4*)x, (s16x4*)xb, 2097152);
  k_twT<<<dim3(192, 64), 256, 0, stream>>>(Wqkv, wT, 2048, 6144);
  k_twT<<<dim3(64, 64), 256, 0, stream>>>(outW, owT, 2048, 2048);
  // QKV: 32 m x 24 n = 768 blocks = exactly 3 blocks/CU co-resident
  k_gw<1, 8, 3><<<768, 256, 0, stream>>>(xb, wT, qkv, 6144, 2048, 3);
  k_ln<<<4096, 256, 0, stream>>>(qkv, qsc, ksc);
  k_vT<<<dim3(32, 32), 256, 0, stream>>>(qkv, vt);
  k_attn<<<dim3(16, 16, 2), 256, 0, stream>>>(qkv, vt, ctx);
  // out-proj: 32 m x 16 n = 512 blocks = exactly 2 blocks/CU
  k_gw<0, 4, 2><<<512, 256, 0, stream>>>(ctx, owT, d_out, 2048, 2048, 2);
}

// Round 8
// 278.467 us; speedup vs baseline: 1.1005x; 1.0106x over previous
//
#include <hip/hip_runtime.h>

// ---------------------------------------------------------------------------
// FlaxAttention: x@Wqkv -> LN(q),LN(k) -> causal flash attn -> ctx@out_W
// B=2 S=2048 D=2048 H=16 Dh=128. All matmuls bf16 MFMA (fp32 accum).
// ---------------------------------------------------------------------------

typedef float f32x4 __attribute__((ext_vector_type(4)));
typedef short s16x8 __attribute__((ext_vector_type(8)));
typedef short s16x4 __attribute__((ext_vector_type(4)));

static __device__ __forceinline__ unsigned short f2bf(float f) {
  unsigned u = __builtin_bit_cast(unsigned, f);
  unsigned r = u + 0x7fffu + ((u >> 16) & 1u);   // RNE
  return (unsigned short)(r >> 16);
}
static __device__ __forceinline__ float bf2f(unsigned short s) {
  unsigned u = ((unsigned)s) << 16;
  return __builtin_bit_cast(float, u);
}

static __device__ __forceinline__ void gload_lds16(const unsigned short* g, unsigned short* l) {
  __builtin_amdgcn_global_load_lds((const __attribute__((address_space(1))) void*)g,
                                   (__attribute__((address_space(3))) void*)l, 16, 0, 0);
}

// --------------------------- fp32 -> bf16 convert ---------------------------
__global__ __launch_bounds__(256) void k_cvt4(const float4* __restrict__ in,
                                              s16x4* __restrict__ out, int n) {
  int i = blockIdx.x * 256 + threadIdx.x;
  if (i >= n) return;
  float4 v = in[i];
  s16x4 o = { (short)f2bf(v.x), (short)f2bf(v.y), (short)f2bf(v.z), (short)f2bf(v.w) };
  out[i] = o;
}

// ------------------- W [K][N] f32 -> W^T [N][K] bf16 ------------------------
__global__ __launch_bounds__(256) void k_twT(const float* __restrict__ in,
                                             unsigned short* __restrict__ out,
                                             int K, int N) {
  __shared__ float tile[32][33];
  const int n0 = blockIdx.x * 32, k0 = blockIdx.y * 32;
  const int tx = threadIdx.x & 31, ty = threadIdx.x >> 5;
#pragma unroll
  for (int rr = 0; rr < 4; ++rr) {
    int kr = ty + rr * 8;
    tile[kr][tx] = in[(size_t)(k0 + kr) * N + n0 + tx];
  }
  __syncthreads();
#pragma unroll
  for (int rr = 0; rr < 4; ++rr) {
    int nr = ty + rr * 8;
    out[(size_t)(n0 + nr) * K + k0 + tx] = f2bf(tile[tx][nr]);
  }
}

// ---- 128 x (NFN*32) GEMM, BK=32, dbuf, 4 waves, 3 blocks/CU (bf16 MFMA) ----
// (unchanged from R6 -- measured best: 110.6us/936TF on QKV, MfmaUtil 40%)
template <int BF16OUT, int NFN, int MINW>
__global__ __launch_bounds__(256, MINW) void k_gw(const unsigned short* __restrict__ A,
                                                  const unsigned short* __restrict__ Bt,
                                                  void* __restrict__ Cout,
                                                  int N, int K, int npx) {
  __shared__ unsigned short sA[2 * 128 * 32];            // 16KB
  __shared__ unsigned short sB[2 * NFN * 32 * 32];       // 32KB @NFN=8
  const int t = threadIdx.x;
  const int wid = t >> 6, lane = t & 63, g = lane >> 4, l15 = lane & 15;
  const int wm = wid >> 1, wn = wid & 1;

  const int xcd = (int)blockIdx.x & 7, idx = (int)blockIdx.x >> 3;
  const int m0 = (idx / npx) * 128;
  const int n0 = (xcd * npx + idx % npx) * (NFN * 32);

  const int u = (t & 7) ^ ((t >> 3) & 7);
  const int srow = 2 * (t >> 3) + (u >> 2);
  const int sk = (u & 3) * 8;
  const unsigned short* pA = A  + (size_t)(m0 + srow) * K + sk;
  const unsigned short* pB = Bt + (size_t)(n0 + srow) * K + sk;

  auto stage = [&](int kt, int buf) {
#pragma unroll
    for (int j = 0; j < 2; ++j)
      gload_lds16(pA + (size_t)(j * 64) * K + kt * 32,
                  sA + buf * 4096 + j * 2048 + t * 8);
#pragma unroll
    for (int j = 0; j < NFN / 2; ++j)
      gload_lds16(pB + (size_t)(j * 64) * K + kt * 32,
                  sB + buf * (NFN * 1024) + j * 2048 + t * 8);
  };

  const int si = (((l15 & 1) * 4 + g) ^ ((l15 >> 1) & 7));
  const int baseA = (wm * 32 + (l15 >> 1)) * 64 + si * 8;
  const int baseB = (wn * NFN * 8 + (l15 >> 1)) * 64 + si * 8;

  f32x4 acc[4][NFN];
#pragma unroll
  for (int fm = 0; fm < 4; ++fm)
#pragma unroll
    for (int fn = 0; fn < NFN; ++fn) acc[fm][fn] = (f32x4){0.f, 0.f, 0.f, 0.f};

  const int NK = K >> 5;
  stage(0, 0); stage(1, 1);
  if constexpr (NFN == 8) asm volatile("s_waitcnt vmcnt(6)" ::: "memory");
  else                    asm volatile("s_waitcnt vmcnt(4)" ::: "memory");
  __builtin_amdgcn_sched_barrier(0);
  __builtin_amdgcn_s_barrier();

  for (int s = 0; s < NK; ++s) {
    const unsigned short* aT = sA + (s & 1) * 4096;
    const unsigned short* bT = sB + (s & 1) * (NFN * 1024);

    s16x8 af[4];
#pragma unroll
    for (int fm = 0; fm < 4; ++fm) af[fm] = *(const s16x8*)&aT[baseA + fm * 512];
    __builtin_amdgcn_s_setprio(1);
#pragma unroll
    for (int fn = 0; fn < NFN; ++fn) {
      s16x8 bf = *(const s16x8*)&bT[baseB + fn * 512];
#pragma unroll
      for (int fm = 0; fm < 4; ++fm)
        acc[fm][fn] = __builtin_amdgcn_mfma_f32_16x16x32_bf16(af[fm], bf, acc[fm][fn], 0, 0, 0);
    }
    __builtin_amdgcn_s_setprio(0);

    __builtin_amdgcn_sched_barrier(0);
    __builtin_amdgcn_s_barrier();            // all reads of buf[s&1] complete
    if (s + 2 < NK) {
      stage(s + 2, s & 1);                   // refill the buffer just freed
      if constexpr (NFN == 8) asm volatile("s_waitcnt vmcnt(6)" ::: "memory");
      else                    asm volatile("s_waitcnt vmcnt(4)" ::: "memory");
    } else if (s + 1 < NK) {
      asm volatile("s_waitcnt vmcnt(0)" ::: "memory");
    }
    __builtin_amdgcn_sched_barrier(0);
    __builtin_amdgcn_s_barrier();            // tile s+1 visible to all
  }

#pragma unroll
  for (int fm = 0; fm < 4; ++fm)
#pragma unroll
    for (int fn = 0; fn < NFN; ++fn)
#pragma unroll
      for (int r = 0; r < 4; ++r) {
        const int row = m0 + wm * 64 + fm * 16 + g * 4 + r;
        const int col = n0 + wn * (NFN * 16) + fn * 16 + l15;
        if (BF16OUT)
          ((unsigned short*)Cout)[(size_t)row * N + col] = f2bf(acc[fm][fn][r]);
        else
          ((float*)Cout)[(size_t)row * N + col] = acc[fm][fn][r];
      }
}

// ----------------- in-place LayerNorm on q,k parts of qkv -------------------
// q gets *= q_scale * (1/sqrt(128))*log2(e) so attn uses exp2 directly.
__global__ __launch_bounds__(256) void k_ln(unsigned short* __restrict__ qkv,
                                            const float* __restrict__ qsc,
                                            const float* __restrict__ ksc) {
  __shared__ float red[8];
  const int t = threadIdx.x;
  const int w = t >> 6;
  unsigned short* base = qkv + (size_t)blockIdx.x * 6144;
#pragma unroll
  for (int part = 0; part < 2; ++part) {
    unsigned short* p = base + part * 2048 + t * 8;
    s16x8 v = *(const s16x8*)p;
    float f[8], s = 0.f, q = 0.f;
#pragma unroll
    for (int j = 0; j < 8; j++) { f[j] = bf2f((unsigned short)v[j]); s += f[j]; q += f[j] * f[j]; }
#pragma unroll
    for (int m = 1; m < 64; m <<= 1) { s += __shfl_xor(s, m); q += __shfl_xor(q, m); }
    __syncthreads();
    if ((t & 63) == 0) { red[w] = s; red[4 + w] = q; }
    __syncthreads();
    s = red[0] + red[1] + red[2] + red[3];
    q = red[4] + red[5] + red[6] + red[7];
    float mean = s * (1.f / 2048.f);
    float var = q * (1.f / 2048.f) - mean * mean;
    float inv = rsqrtf(var + 1e-6f);
    const float* sc = part ? ksc : qsc;
    float extra = part ? 1.0f : 0.12751743f;  // (1/sqrt(128))*log2(e)
    s16x8 o;
#pragma unroll
    for (int j = 0; j < 8; j++) o[j] = (short)f2bf((f[j] - mean) * inv * (sc[t * 8 + j] * extra));
    *(s16x8*)p = o;
  }
}

// ------ v part of qkv (bf16) -> v_t [b][h][d][2048], PV-fragment order ------
__global__ __launch_bounds__(256) void k_vT(const unsigned short* __restrict__ qkv,
                                            unsigned short* __restrict__ vt) {
  __shared__ unsigned short tl[64][136];
  const int bh = blockIdx.y;
  const int b = bh >> 4, h = bh & 15;
  const int s0 = blockIdx.x * 64;
  const int t = threadIdx.x;
#pragma unroll
  for (int it = 0; it < 4; ++it) {
    int flat = it * 256 + t;
    int r = flat >> 4, c = flat & 15;
    s16x8 v = *(const s16x8*)(qkv + (size_t)(b * 2048 + s0 + r) * 6144 + 4096 + h * 128 + c * 8);
    *((s16x8*)&tl[r][c * 8]) = v;
  }
  __syncthreads();
#pragma unroll
  for (int it = 0; it < 4; ++it) {
    int flat = it * 256 + t;
    int d = flat >> 3, cs = flat & 7;
    s16x8 o;
#pragma unroll
    for (int e = 0; e < 8; e++) {
      int key = (cs >> 2) * 32 + (e >> 2) * 16 + (cs & 3) * 4 + (e & 3);
      o[e] = (short)tl[key][d];
    }
    *(s16x8*)(vt + (size_t)(bh * 128 + d) * 2048 + s0 + cs * 8) = o;
  }
}

// --------------------------- causal flash attention -------------------------
// QBLK=128 (8 waves x 16 q-rows), KVBLK=64, dbuf LDS 64KB, 512 threads.
// Halves KV re-read traffic vs QBLK=64 (540MB -> 278MB of L2/L3): each staged
// K/V tile now feeds 8 waves instead of 4. Grid = 8 pairs x 16 h x 2 b = 256
// blocks = exactly 1/CU, uniform 34 iterations/block (paired q-tiles), no tail.
// Per-wave math identical to the verified R2-R6 kernel (w now in [0,8)).
__global__ __launch_bounds__(512) void k_attn(const unsigned short* __restrict__ qkv,
                                              const unsigned short* __restrict__ vt,
                                              unsigned short* __restrict__ ctx) {
  __shared__ unsigned short sK[2][64 * 128];
  __shared__ unsigned short sV[2][128 * 64];
  const int t = threadIdx.x;
  const int w = t >> 6, lane = t & 63, g = lane >> 4, l15 = lane & 15;
  const int pair = blockIdx.x, h = blockIdx.y, b = blockIdx.z;
  const int qt0 = 15 - pair, qt1 = pair;        // q-tiles of 128 rows
  const int n0 = 2 * qt0 + 2;                   // KV-iters in segment 0
  const int NT = 34;                            // n0 + 2*qt1+2
  const unsigned short* kbase = qkv + (size_t)(b * 2048) * 6144 + 2048 + h * 128;
  const unsigned short* vbase = vt + (size_t)((b * 16 + h) * 128) * 2048;

  auto issue_kv = [&](int k0, int bufi) {
#pragma unroll
    for (int it2 = 0; it2 < 2; ++it2) {         // K tile 64x128, swz c^(r&15)
      int flat = it2 * 512 + t;
      int r = flat >> 4, c = flat & 15;
      gload_lds16(kbase + (size_t)(k0 + r) * 6144 + ((c ^ (r & 15)) * 8),
                  (unsigned short*)&sK[bufi][flat * 8]);
    }
#pragma unroll
    for (int it2 = 0; it2 < 2; ++it2) {         // V tile 128d x 64, swz z^(d&7)
      int flat = it2 * 512 + t;
      int d = flat >> 3, z = flat & 7;
      gload_lds16(vbase + (size_t)d * 2048 + k0 + ((z ^ (d & 7)) * 8),
                  (unsigned short*)&sV[bufi][flat * 8]);
    }
  };

  s16x8 bq[4];
  auto load_q = [&](int q0) {
#pragma unroll
    for (int ks = 0; ks < 4; ++ks)
      bq[ks] = *(const s16x8*)(qkv + (size_t)(b * 2048 + q0 + w * 16 + l15) * 6144 +
                               h * 128 + (ks * 4 + g) * 8);
  };

  f32x4 o[8];
  float mrun, lrun;
  auto reset_state = [&]() {
#pragma unroll
    for (int nd = 0; nd < 8; ++nd) o[nd] = (f32x4){0.f, 0.f, 0.f, 0.f};
    mrun = -INFINITY; lrun = 0.f;
  };
  auto write_o = [&](int q0) {
    float ivr[4];
#pragma unroll
    for (int r = 0; r < 4; ++r) ivr[r] = 1.0f / __shfl(lrun, 4 * g + r);
#pragma unroll
    for (int nd = 0; nd < 8; ++nd) {
      const int col = h * 128 + nd * 16 + l15;
#pragma unroll
      for (int r = 0; r < 4; ++r) {
        const int row = b * 2048 + q0 + w * 16 + 4 * g + r;
        ctx[(size_t)row * 2048 + col] = f2bf(o[nd][r] * ivr[r]);
      }
    }
  };

  reset_state();
  load_q(qt0 * 128);
  issue_kv(0, 0);
  int cur = 0;

  for (int it = 0; it < NT; ++it) {
    const int seg = (it < n0) ? 0 : 1;
    const int qt = seg ? qt1 : qt0;
    const int kt = seg ? it - n0 : it;          // KV-tile idx within segment

    if (it + 1 < NT) {
      const int kn = (it + 1 < n0) ? it + 1 : it + 1 - n0;
      issue_kv(kn * 64, cur ^ 1);
      asm volatile("s_waitcnt vmcnt(4)" ::: "memory");  // current tile landed
    } else {
      asm volatile("s_waitcnt vmcnt(0)" ::: "memory");
    }
    __builtin_amdgcn_sched_barrier(0);
    __builtin_amdgcn_s_barrier();

    if (seg == 1 && kt == 0) {
      write_o(qt0 * 128);
      reset_state();
      load_q(qt1 * 128);
    }

    const unsigned short* sKc = &sK[cur][0];
    const unsigned short* sVc = &sV[cur][0];

    f32x4 st[4];
#pragma unroll
    for (int mi = 0; mi < 4; ++mi) st[mi] = (f32x4){0.f, 0.f, 0.f, 0.f};
#pragma unroll
    for (int mi = 0; mi < 4; ++mi) {
#pragma unroll
      for (int ks = 0; ks < 4; ++ks) {
        s16x8 ak = *(const s16x8*)&sKc[(mi * 16 + l15) * 128 + (((ks * 4 + g) ^ l15) * 8)];
        st[mi] = __builtin_amdgcn_mfma_f32_16x16x32_bf16(ak, bq[ks], st[mi], 0, 0, 0);
      }
    }
    // st[mi][r] = S^T[key = kt*64 + mi*16+4g+r][q = qt*128 + w*16+l15]

    if (kt >= 2 * qt) {                          // diagonal band: causal mask
      const int qglob = qt * 128 + w * 16 + l15;
#pragma unroll
      for (int mi = 0; mi < 4; ++mi)
#pragma unroll
        for (int r = 0; r < 4; ++r)
          if (kt * 64 + mi * 16 + 4 * g + r > qglob) st[mi][r] = -INFINITY;
    }

    float mt = -INFINITY;
#pragma unroll
    for (int mi = 0; mi < 4; ++mi)
#pragma unroll
      for (int r = 0; r < 4; ++r) mt = fmaxf(mt, st[mi][r]);
    mt = fmaxf(mt, __shfl_xor(mt, 16));
    mt = fmaxf(mt, __shfl_xor(mt, 32));

    if (!__all(mt <= mrun + 8.f)) {              // defer-max: rescale rarely
      const float mnew = fmaxf(mrun, mt);
      const float alpha = exp2f(mrun - mnew);
      lrun *= alpha;
      float ar[4];
#pragma unroll
      for (int r = 0; r < 4; ++r) ar[r] = __shfl(alpha, 4 * g + r);
#pragma unroll
      for (int nd = 0; nd < 8; ++nd)
#pragma unroll
        for (int r = 0; r < 4; ++r) o[nd][r] *= ar[r];
      mrun = mnew;
    }

    float ls = 0.f;
#pragma unroll
    for (int mi = 0; mi < 4; ++mi)
#pragma unroll
      for (int r = 0; r < 4; ++r) {
        float pp = exp2f(st[mi][r] - mrun);
        st[mi][r] = pp;
        ls += pp;
      }
    ls += __shfl_xor(ls, 16);
    ls += __shfl_xor(ls, 32);
    lrun += ls;

    s16x8 pa01, pa23;  // P as PV A-operand: slot j <-> key (j>>2)*16+4g+(j&3)
#pragma unroll
    for (int j = 0; j < 8; ++j) {
      pa01[j] = (short)f2bf(st[j >> 2][j & 3]);
      pa23[j] = (short)f2bf(st[2 + (j >> 2)][j & 3]);
    }

#pragma unroll
    for (int nd = 0; nd < 8; ++nd) {
      const int d = nd * 16 + l15;
      const int zs = d & 7;
      s16x8 bv0 = *(const s16x8*)&sVc[d * 64 + ((g ^ zs) * 8)];
      s16x8 bv1 = *(const s16x8*)&sVc[d * 64 + (((4 + g) ^ zs) * 8)];
      o[nd] = __builtin_amdgcn_mfma_f32_16x16x32_bf16(pa01, bv0, o[nd], 0, 0, 0);
      o[nd] = __builtin_amdgcn_mfma_f32_16x16x32_bf16(pa23, bv1, o[nd], 0, 0, 0);
    }

    __builtin_amdgcn_sched_barrier(0);
    __builtin_amdgcn_s_barrier();                // reads of buf[cur] done
    cur ^= 1;
  }
  write_o(qt1 * 128);
}

// ---------------------------------------------------------------------------
extern "C" void kernel_launch(void* const* d_in, const int* in_sizes, int n_in,
                              void* d_out, int out_size, void* d_ws, size_t ws_size,
                              hipStream_t stream) {
  (void)in_sizes; (void)n_in; (void)out_size; (void)ws_size;
  const float* x    = (const float*)d_in[0];
  const float* Wqkv = (const float*)d_in[1];
  const float* qsc  = (const float*)d_in[2];
  const float* ksc  = (const float*)d_in[3];
  const float* outW = (const float*)d_in[4];

  char* ws = (char*)d_ws;
  unsigned short* xb  = (unsigned short*)(ws);              // 16.8MB (reused as ctx)
  unsigned short* wT  = (unsigned short*)(ws + 16777216);   // 25.2MB  Wqkv^T bf16
  unsigned short* owT = (unsigned short*)(ws + 41943040);   // 8.4MB   out_W^T bf16
  unsigned short* qkv = (unsigned short*)(ws + 50331648);   // 50.3MB  qkv bf16 (LN in place)
  unsigned short* vt  = (unsigned short*)(ws + 100663296);  // 16.8MB  v^T per head
  unsigned short* ctx = xb;                                 // x dead after QKV GEMM

  k_cvt4<<<8192, 256, 0, stream>>>((const float4*)x, (s16x4*)xb, 2097152);
  k_twT<<<dim3(192, 64), 256, 0, stream>>>(Wqkv, wT, 2048, 6144);
  k_twT<<<dim3(64, 64), 256, 0, stream>>>(outW, owT, 2048, 2048);
  // QKV: 32 m x 24 n = 768 blocks = exactly 3 blocks/CU co-resident
  k_gw<1, 8, 3><<<768, 256, 0, stream>>>(xb, wT, qkv, 6144, 2048, 3);
  k_ln<<<4096, 256, 0, stream>>>(qkv, qsc, ksc);
  k_vT<<<dim3(32, 32), 256, 0, stream>>>(qkv, vt);
  // attn: 8 pairs x 16 h x 2 b = 256 blocks of 512 thr = 1/CU, 34 iters each
  k_attn<<<dim3(8, 16, 2), 512, 0, stream>>>(qkv, vt, ctx);
  // out-proj: 32 m x 16 n = 512 blocks = exactly 2 blocks/CU
  k_gw<0, 4, 2><<<512, 256, 0, stream>>>(ctx, owT, d_out, 2048, 2048, 2);
}